// Round 4
// baseline (76.710 us; speedup 1.0000x reference)
//
#include <hip/hip_runtime.h>

// KVEmbedding gather: out[b,l,:] = table[indices[b,l], :]
// indices: int32 [4096*200], table: float32 [1'000'000 x 64], out: float32 [4096*200*64]
// Exact-fit grid: one 16 B float4 chunk per thread (16 threads per 64-float row).
// Wave = 4 rows; each global instruction moves 4 x 256 B contiguous segments.
// Round-3 post-mortem: nt-stores regressed 3% -> reverted to plain stores.

typedef float f32x4 __attribute__((ext_vector_type(4)));

__global__ __launch_bounds__(256) void kv_gather_kernel(
    const int* __restrict__ idx,
    const float* __restrict__ table,
    float* __restrict__ out)
{
    const long long i = (long long)blockIdx.x * blockDim.x + threadIdx.x;
    const long long row = i >> 4;
    const int sub = (int)(i & 15);
    const long long t = (long long)idx[row];
    const f32x4* __restrict__ src = reinterpret_cast<const f32x4*>(table + t * 64);
    f32x4* __restrict__ dst = reinterpret_cast<f32x4*>(out + row * 64);
    dst[sub] = src[sub];
}

extern "C" void kernel_launch(void* const* d_in, const int* in_sizes, int n_in,
                              void* d_out, int out_size, void* d_ws, size_t ws_size,
                              hipStream_t stream)
{
    const int*   idx   = (const int*)d_in[0];    // indices [4096*200]
    const float* table = (const float*)d_in[1];  // table [1e6 * 64]
    float*       out   = (float*)d_out;          // [4096*200*64]

    const long long nrows = in_sizes[0];          // 819200
    const long long total = nrows << 4;           // 13,107,200 float4 chunks
    const int block = 256;
    const long long nblk = (total + block - 1) / block;  // 51200 blocks, exact fit

    kv_gather_kernel<<<(int)nblk, block, 0, stream>>>(idx, table, out);
}

// Round 5
// 74.609 us; speedup vs baseline: 1.0282x; 1.0282x over previous
//
#include <hip/hip_runtime.h>

// KVEmbedding gather: out[b,l,:] = table[indices[b,l], :]
// indices: int32 [4096*200], table: float32 [1'000'000 x 64], out: float32 [4096*200*64]
// 16 threads per 64-float row, one float4 chunk each; 2048 blocks x 256 thr,
// exactly 25 grid-stride iterations. All 25 per-thread indices are preloaded
// into registers (25 loads in flight) before the gather loop, so the gathers
// are independent and pipeline deeply instead of serializing on idx->gather.

typedef float f32x4 __attribute__((ext_vector_type(4)));

constexpr int  BLOCK  = 256;
constexpr int  NBLK   = 2048;             // 8 blocks/CU on 256 CUs
constexpr int  ITERS  = 25;               // 819200*16 / (2048*256)
constexpr long long STRIDE = (long long)NBLK * BLOCK;

__global__ __launch_bounds__(BLOCK) void kv_gather_pipelined(
    const int* __restrict__ idx,
    const float* __restrict__ table,
    float* __restrict__ out)
{
    const long long i0 = (long long)blockIdx.x * BLOCK + threadIdx.x;

    int t[ITERS];
#pragma unroll
    for (int k = 0; k < ITERS; ++k) {
        const long long i = i0 + (long long)k * STRIDE;
        t[k] = idx[i >> 4];               // 25 independent loads, all in flight
    }

#pragma unroll
    for (int k = 0; k < ITERS; ++k) {
        const long long i   = i0 + (long long)k * STRIDE;
        const long long row = i >> 4;
        const int       sub = (int)(i & 15);
        const f32x4* __restrict__ src =
            reinterpret_cast<const f32x4*>(table + (long long)t[k] * 64);
        f32x4* __restrict__ dst = reinterpret_cast<f32x4*>(out + row * 64);
        dst[sub] = src[sub];              // 25 independent gather+store pairs
    }
}

// Generic fallback (shape-safe), same structure as the round-1 kernel.
__global__ __launch_bounds__(BLOCK) void kv_gather_generic(
    const int* __restrict__ idx,
    const float* __restrict__ table,
    float* __restrict__ out,
    long long nrows)
{
    const long long total = nrows << 4;
    long long i = (long long)blockIdx.x * blockDim.x + threadIdx.x;
    const long long stride = (long long)gridDim.x * blockDim.x;
    for (; i < total; i += stride) {
        const long long row = i >> 4;
        const int sub = (int)(i & 15);
        const long long t = (long long)idx[row];
        const f32x4* __restrict__ src =
            reinterpret_cast<const f32x4*>(table + t * 64);
        f32x4* __restrict__ dst = reinterpret_cast<f32x4*>(out + row * 64);
        dst[sub] = src[sub];
    }
}

extern "C" void kernel_launch(void* const* d_in, const int* in_sizes, int n_in,
                              void* d_out, int out_size, void* d_ws, size_t ws_size,
                              hipStream_t stream)
{
    const int*   idx   = (const int*)d_in[0];    // indices [4096*200]
    const float* table = (const float*)d_in[1];  // table [1e6 * 64]
    float*       out   = (float*)d_out;          // [4096*200*64]

    const long long nrows = in_sizes[0];          // 819200
    const long long total = nrows << 4;

    if (total == STRIDE * ITERS) {
        kv_gather_pipelined<<<NBLK, BLOCK, 0, stream>>>(idx, table, out);
    } else {
        long long nblk = (total + BLOCK - 1) / BLOCK;
        if (nblk > NBLK) nblk = NBLK;
        kv_gather_generic<<<(int)nblk, BLOCK, 0, stream>>>(idx, table, out, nrows);
    }
}

// Round 6
// 71.894 us; speedup vs baseline: 1.0670x; 1.0378x over previous
//
#include <hip/hip_runtime.h>

// KVEmbedding gather: out[b,l,:] = table[indices[b,l], :]
// indices: int32 [4096*200], table: float32 [1'000'000 x 64], out: float32 [4096*200*64]
// 16 threads cooperate on one 64-float row; each thread moves one float4 (16 B).
// Resident grid (2048 blocks = 8/CU) + grid-stride loop. This exact structure
// measured best across 5 rounds (71.6 us):
//   - nt-stores:        73.8 us (-3%)  [L2/L3 write-allocate not the limiter]
//   - exact-fit grid:   76.7 us (-7%)  [tiny one-shot blocks lose to residency]
//   - idx reg-preload:  74.6 us (-4%)  [idx->gather chain not the limiter]
// Floor arithmetic: 210 MB write + ~143-210 MB random 256 B table reads + 3 MB
// idx => 5.0-5.9 TB/s effective at 71.6 us, at the mixed-stream HBM ceiling.

typedef float f32x4 __attribute__((ext_vector_type(4)));

__global__ __launch_bounds__(256) void kv_gather_kernel(
    const int* __restrict__ idx,
    const float* __restrict__ table,
    float* __restrict__ out,
    long long nrows)
{
    const long long total = nrows << 4;  // 16 float4 chunks per row
    long long i = (long long)blockIdx.x * blockDim.x + threadIdx.x;
    const long long stride = (long long)gridDim.x * blockDim.x;
    for (; i < total; i += stride) {
        const long long row = i >> 4;
        const int sub = (int)(i & 15);
        const long long t = (long long)idx[row];
        const f32x4* __restrict__ src =
            reinterpret_cast<const f32x4*>(table + t * 64);
        f32x4* __restrict__ dst =
            reinterpret_cast<f32x4*>(out + row * 64);
        dst[sub] = src[sub];
    }
}

extern "C" void kernel_launch(void* const* d_in, const int* in_sizes, int n_in,
                              void* d_out, int out_size, void* d_ws, size_t ws_size,
                              hipStream_t stream)
{
    const int*   idx   = (const int*)d_in[0];    // indices [4096*200]
    const float* table = (const float*)d_in[1];  // table [1e6 * 64]
    float*       out   = (float*)d_out;          // [4096*200*64]

    const long long nrows = in_sizes[0];          // 819200
    const long long total = nrows << 4;           // float4 chunks

    const int block = 256;
    long long nblk = (total + block - 1) / block;
    const long long maxblk = 256LL * 8;           // 8 blocks/CU = full residency
    if (nblk > maxblk) nblk = maxblk;

    kv_gather_kernel<<<(int)nblk, block, 0, stream>>>(idx, table, out, nrows);
}